// Round 9
// baseline (116.772 us; speedup 1.0000x reference)
//
#include <hip/hip_runtime.h>
#include <hip/hip_bf16.h>

// FactorizedTrilinear: out[b,z,x,c,dv] = sum_e p1[b,z,dv,e] p2[b,x,dv,e] p3[b,c,dv,e]
// B=4, Z=128, DV=4, IN=512, R=256. Output 4*128^3*4 fp32 = 134 MB (write floor
// ~19 us at the 6.9 TB/s pure-write rate the harness fill demonstrates).
// R9 (tri): R8 structure with (1) double-buffered sT -> ONE barrier per z-iter,
// (2) p1 row read direct from global (wave-uniform -> L1 broadcast; sP1 LDS
// dropped, LDS 49.5->33 KB), (3) launch_bounds(256,4) -> 4 blocks/CU (grid 1024
// = exactly one co-resident round). proj unchanged from R8 (known-correct).

typedef _Float16 f16;
typedef __attribute__((ext_vector_type(8)))  _Float16 f16x8;
typedef __attribute__((ext_vector_type(4)))  float    f32x4;
typedef __attribute__((ext_vector_type(16))) float    f32x16;

// ---------------- Stage 1: projections via 32x32x16 f16 MFMA ----------------
// GEMM per matrix: M=2048 (m = b*512 + z*4 + dv), N=256, K=512.
// Block 256 thr = 4 waves (2m x 2n) -> tile 64m x 64n; grid (32,4,3).
// Per 32-k chunk: stage W[32k][64n] -> LDS as sWt[n][k] f16 (row stride 40),
// A-frag per-lane direct from x (f32->f16).
__global__ __launch_bounds__(256) void proj_kernel(
    const float* __restrict__ x1, const float* __restrict__ x2, const float* __restrict__ x3,
    const float* __restrict__ W1, const float* __restrict__ b1,
    const float* __restrict__ W2, const float* __restrict__ b2,
    const float* __restrict__ W3, const float* __restrict__ b3,
    f16* __restrict__ p1, f16* __restrict__ p2, f16* __restrict__ p3) {
    const int mat = blockIdx.z;
    const float* __restrict__ x    = (mat == 0) ? x1 : (mat == 1) ? x2 : x3;
    const float* __restrict__ W    = (mat == 0) ? W1 : (mat == 1) ? W2 : W3;
    const float* __restrict__ bias = (mat == 0) ? b1 : (mat == 1) ? b2 : b3;
    f16* __restrict__ p = (mat == 0) ? p1 : (mat == 1) ? p2 : p3;

    const int tid  = threadIdx.x;
    const int lane = tid & 63;
    const int w    = tid >> 6;
    const int ln   = lane & 31;
    const int kq   = lane >> 5;
    const int m0   = blockIdx.x * 64 + (w >> 1) * 32;
    const int n0b  = blockIdx.y * 64;
    const int n0   = n0b + (w & 1) * 32;

    __shared__ f16 sWt[64 * 40];   // [n][k], row stride 40 f16

    f32x16 acc;
#pragma unroll
    for (int i = 0; i < 16; ++i) acc[i] = 0.f;

    const int snn = tid & 63, skk0 = tid >> 6;

#pragma unroll 1
    for (int ch = 0; ch < 16; ++ch) {
        const int k0 = ch * 32;
        // stage W chunk: [32k][64n] -> sWt[n][k] f16
#pragma unroll
        for (int j = 0; j < 8; ++j) {
            const int kk = skk0 + 4 * j;
            sWt[snn * 40 + kk] = (f16)W[(size_t)(k0 + kk) * 256 + n0b + snn];
        }
        __syncthreads();
#pragma unroll
        for (int ks = 0; ks < 2; ++ks) {
            const float* X = x + (size_t)(m0 + ln) * 512 + k0 + ks * 16 + kq * 8;
            f32x4 a0 = *(const f32x4*)X;
            f32x4 a1 = *(const f32x4*)(X + 4);
            f16x8 av;
            av[0] = (f16)a0[0]; av[1] = (f16)a0[1]; av[2] = (f16)a0[2]; av[3] = (f16)a0[3];
            av[4] = (f16)a1[0]; av[5] = (f16)a1[1]; av[6] = (f16)a1[2]; av[7] = (f16)a1[3];
            f16x8 bv = *(const f16x8*)&sWt[((w & 1) * 32 + ln) * 40 + ks * 16 + kq * 8];
            acc = __builtin_amdgcn_mfma_f32_32x32x16_f16(av, bv, acc, 0, 0, 0);
        }
        __syncthreads();
    }

    // C/D map (m74/m101): col = lane&31 -> n, row = (i&3)+8*(i>>2)+4*kq -> m.
    const int n = n0 + ln;
    const float bn = bias[n];
#pragma unroll
    for (int i = 0; i < 16; ++i) {
        const int m  = m0 + (i & 3) + 8 * (i >> 2) + 4 * kq;
        const int bb = m >> 9, z = (m >> 2) & 127, dv = m & 3;
        p[((bb * 4 + dv) * 128 + z) * 256 + n] = (f16)(acc[i] + bn);
    }
}

// ---------------- Stage 2: trilinear ----------------
// Grid = b(4) x xt(4) x ct(4) x zg(16) = 1024 blocks; 256 thr = 4 waves,
// wave w = dv. Wave: 32x x 32c x 8z x 1dv.
// bq[16] (p3 c-rows, full K=256) register-resident, z-invariant. pv (p2 x-row)
// and u (p1 z-row, wave-uniform) streamed from L1 each z. Per z: 16 MFMA ->
// acc -> sT[zi&1][dv][x][c] (stride 33), ONE barrier, transposed f32x4-over-dv
// read -> coalesced 16B nontemporal stores.
__global__ __launch_bounds__(256, 4) void tri_kernel(
    const f16* __restrict__ p1, const f16* __restrict__ p2,
    const f16* __restrict__ p3, float* __restrict__ out) {
    const int bi = blockIdx.x;
    const int zg = bi & 15;
    const int ct = (bi >> 4) & 3;
    const int xt = (bi >> 6) & 3;
    const int b  = bi >> 8;

    const int tid  = threadIdx.x;
    const int lane = tid & 63;
    const int w    = tid >> 6;          // = dv
    const int ln   = lane & 31;
    const int kq   = lane >> 5;
    const int x0   = xt * 32;
    const int c0   = ct * 32;
    const int z0   = zg * 8;
    const int sl   = b * 4 + w;

    __shared__ float sT[2][4 * 32 * 33];   // 2 x 16.5 KB transpose buffers

    // ---- prologue: p3 c-row fragments, full K=256, register-resident ----
    f16x8 bq[16];
    const f16* P3r = p3 + ((sl * 128 + c0 + ln) << 8) + kq * 8;
#pragma unroll
    for (int ks = 0; ks < 16; ++ks) bq[ks] = *(const f16x8*)(P3r + ks * 16);

    const f16* P2r = p2 + ((sl * 128 + x0 + ln) << 8) + kq * 8;   // per-lane x row
    const f16* P1r = p1 + ((sl * 128 + z0) << 8) + kq * 8;        // z rows, +256/z

    const int cl = tid & 31, xg = tid >> 5;

#pragma unroll 1
    for (int zi = 0; zi < 8; ++zi) {
        f32x16 acc;
#pragma unroll
        for (int i = 0; i < 16; ++i) acc[i] = 0.f;

#pragma unroll
        for (int ks = 0; ks < 16; ++ks) {
            f16x8 u  = *(const f16x8*)(P1r + zi * 256 + ks * 16);   // uniform -> L1 bcast
            f16x8 pv = *(const f16x8*)(P2r + ks * 16);              // L1-resident
            f16x8 af = u * pv;                                       // 4x v_pk_mul_f16
            acc = __builtin_amdgcn_mfma_f32_32x32x16_f16(af, bq[ks], acc, 0, 0, 0);
        }

        // ---- acc -> LDS [dv][x][c] (stride 33; 2-way max = free) ----
        float* T = sT[zi & 1];
#pragma unroll
        for (int i = 0; i < 16; ++i) {
            const int xl = (i & 3) + 8 * (i >> 2) + 4 * kq;
            T[w * 1056 + xl * 33 + ln] = acc[i];
        }
        __syncthreads();

        // ---- transposed read + coalesced f32x4-over-dv stores ----
        const int z = z0 + zi;
#pragma unroll
        for (int j = 0; j < 4; ++j) {
            const int xl = xg * 4 + j;
            f32x4 v;
            v[0] = T[0 * 1056 + xl * 33 + cl];
            v[1] = T[1 * 1056 + xl * 33 + cl];
            v[2] = T[2 * 1056 + xl * 33 + cl];
            v[3] = T[3 * 1056 + xl * 33 + cl];
            const size_t idx = (size_t)((b * 128 + z) * 128 + x0 + xl) * 128 + c0 + cl;
            __builtin_nontemporal_store(v, (f32x4*)(out + idx * 4));
        }
        // no second barrier: next iter writes the other sT buffer
    }
}

extern "C" void kernel_launch(void* const* d_in, const int* in_sizes, int n_in,
                              void* d_out, int out_size, void* d_ws, size_t ws_size,
                              hipStream_t stream) {
    const float* x1 = (const float*)d_in[0];
    const float* x2 = (const float*)d_in[1];
    const float* x3 = (const float*)d_in[2];
    const float* W1 = (const float*)d_in[3];
    const float* b1 = (const float*)d_in[4];
    const float* W2 = (const float*)d_in[5];
    const float* b2 = (const float*)d_in[6];
    const float* W3 = (const float*)d_in[7];
    const float* b3 = (const float*)d_in[8];

    char* ws = (char*)d_ws;
    f16* p1 = (f16*)ws;                            // [16][128][256] f16 = 1 MB
    f16* p2 = (f16*)(ws + (1u << 20));             // 1 MB
    f16* p3 = (f16*)(ws + 2u * (1u << 20));        // 1 MB

    proj_kernel<<<dim3(32, 4, 3), 256, 0, stream>>>(x1, x2, x3, W1, b1, W2, b2, W3, b3,
                                                    p1, p2, p3);
    tri_kernel<<<dim3(1024), 256, 0, stream>>>(p1, p2, p3, (float*)d_out);
}

// Round 10
// 82.215 us; speedup vs baseline: 1.4203x; 1.4203x over previous
//
#include <hip/hip_runtime.h>
#include <hip/hip_bf16.h>

// FactorizedTrilinear: out[b,z,x,c,dv] = sum_e p1[b,z,dv,e] p2[b,x,dv,e] p3[b,c,dv,e]
// B=4, Z=128, DV=4, IN=512, R=256. Output 4*128^3*4 fp32 = 134 MB (write floor
// ~19 us at the 6.9 TB/s pure-write rate the harness fill demonstrates).
// R10: R9 structure, but __launch_bounds__(256,3): R9's (256,4) capped VGPR at
// 64 and SPILLED bq[16] (64 VGPRs) -> scratch traffic exploded FETCH_SIZE
// 8.7->167 MB, WRITE 131->172 MB. (256,3) gives ~168-reg ceiling (need ~115),
// no spill, 3 blocks/CU via 33 KB LDS. Everything else unchanged from R9:
// dbuf sT one-barrier epilogue, p1/p2 streamed from L1, bq register-resident.

typedef _Float16 f16;
typedef __attribute__((ext_vector_type(8)))  _Float16 f16x8;
typedef __attribute__((ext_vector_type(4)))  float    f32x4;
typedef __attribute__((ext_vector_type(16))) float    f32x16;

// ---------------- Stage 1: projections via 32x32x16 f16 MFMA ----------------
// GEMM per matrix: M=2048 (m = b*512 + z*4 + dv), N=256, K=512.
// Block 256 thr = 4 waves (2m x 2n) -> tile 64m x 64n; grid (32,4,3).
// Per 32-k chunk: stage W[32k][64n] -> LDS as sWt[n][k] f16 (row stride 40),
// A-frag per-lane direct from x (f32->f16).
__global__ __launch_bounds__(256) void proj_kernel(
    const float* __restrict__ x1, const float* __restrict__ x2, const float* __restrict__ x3,
    const float* __restrict__ W1, const float* __restrict__ b1,
    const float* __restrict__ W2, const float* __restrict__ b2,
    const float* __restrict__ W3, const float* __restrict__ b3,
    f16* __restrict__ p1, f16* __restrict__ p2, f16* __restrict__ p3) {
    const int mat = blockIdx.z;
    const float* __restrict__ x    = (mat == 0) ? x1 : (mat == 1) ? x2 : x3;
    const float* __restrict__ W    = (mat == 0) ? W1 : (mat == 1) ? W2 : W3;
    const float* __restrict__ bias = (mat == 0) ? b1 : (mat == 1) ? b2 : b3;
    f16* __restrict__ p = (mat == 0) ? p1 : (mat == 1) ? p2 : p3;

    const int tid  = threadIdx.x;
    const int lane = tid & 63;
    const int w    = tid >> 6;
    const int ln   = lane & 31;
    const int kq   = lane >> 5;
    const int m0   = blockIdx.x * 64 + (w >> 1) * 32;
    const int n0b  = blockIdx.y * 64;
    const int n0   = n0b + (w & 1) * 32;

    __shared__ f16 sWt[64 * 40];   // [n][k], row stride 40 f16

    f32x16 acc;
#pragma unroll
    for (int i = 0; i < 16; ++i) acc[i] = 0.f;

    const int snn = tid & 63, skk0 = tid >> 6;

#pragma unroll 1
    for (int ch = 0; ch < 16; ++ch) {
        const int k0 = ch * 32;
        // stage W chunk: [32k][64n] -> sWt[n][k] f16
#pragma unroll
        for (int j = 0; j < 8; ++j) {
            const int kk = skk0 + 4 * j;
            sWt[snn * 40 + kk] = (f16)W[(size_t)(k0 + kk) * 256 + n0b + snn];
        }
        __syncthreads();
#pragma unroll
        for (int ks = 0; ks < 2; ++ks) {
            const float* X = x + (size_t)(m0 + ln) * 512 + k0 + ks * 16 + kq * 8;
            f32x4 a0 = *(const f32x4*)X;
            f32x4 a1 = *(const f32x4*)(X + 4);
            f16x8 av;
            av[0] = (f16)a0[0]; av[1] = (f16)a0[1]; av[2] = (f16)a0[2]; av[3] = (f16)a0[3];
            av[4] = (f16)a1[0]; av[5] = (f16)a1[1]; av[6] = (f16)a1[2]; av[7] = (f16)a1[3];
            f16x8 bv = *(const f16x8*)&sWt[((w & 1) * 32 + ln) * 40 + ks * 16 + kq * 8];
            acc = __builtin_amdgcn_mfma_f32_32x32x16_f16(av, bv, acc, 0, 0, 0);
        }
        __syncthreads();
    }

    // C/D map (m74/m101): col = lane&31 -> n, row = (i&3)+8*(i>>2)+4*kq -> m.
    const int n = n0 + ln;
    const float bn = bias[n];
#pragma unroll
    for (int i = 0; i < 16; ++i) {
        const int m  = m0 + (i & 3) + 8 * (i >> 2) + 4 * kq;
        const int bb = m >> 9, z = (m >> 2) & 127, dv = m & 3;
        p[((bb * 4 + dv) * 128 + z) * 256 + n] = (f16)(acc[i] + bn);
    }
}

// ---------------- Stage 2: trilinear ----------------
// Grid = b(4) x xt(4) x ct(4) x zg(16) = 1024 blocks; 256 thr = 4 waves,
// wave w = dv. Wave: 32x x 32c x 8z x 1dv.
// bq[16] (p3 c-rows, full K=256) register-resident, z-invariant. pv (p2 x-row)
// and u (p1 z-row, wave-uniform) streamed from L1 each z. Per z: 16 MFMA ->
// acc -> sT[zi&1][dv][x][c] (stride 33), ONE barrier, transposed f32x4-over-dv
// read -> coalesced 16B nontemporal stores.
__global__ __launch_bounds__(256, 3) void tri_kernel(
    const f16* __restrict__ p1, const f16* __restrict__ p2,
    const f16* __restrict__ p3, float* __restrict__ out) {
    const int bi = blockIdx.x;
    const int zg = bi & 15;
    const int ct = (bi >> 4) & 3;
    const int xt = (bi >> 6) & 3;
    const int b  = bi >> 8;

    const int tid  = threadIdx.x;
    const int lane = tid & 63;
    const int w    = tid >> 6;          // = dv
    const int ln   = lane & 31;
    const int kq   = lane >> 5;
    const int x0   = xt * 32;
    const int c0   = ct * 32;
    const int z0   = zg * 8;
    const int sl   = b * 4 + w;

    __shared__ float sT[2][4 * 32 * 33];   // 2 x 16.5 KB transpose buffers

    // ---- prologue: p3 c-row fragments, full K=256, register-resident ----
    f16x8 bq[16];
    const f16* P3r = p3 + ((sl * 128 + c0 + ln) << 8) + kq * 8;
#pragma unroll
    for (int ks = 0; ks < 16; ++ks) bq[ks] = *(const f16x8*)(P3r + ks * 16);

    const f16* P2r = p2 + ((sl * 128 + x0 + ln) << 8) + kq * 8;   // per-lane x row
    const f16* P1r = p1 + ((sl * 128 + z0) << 8) + kq * 8;        // z rows, +256/z

    const int cl = tid & 31, xg = tid >> 5;

#pragma unroll 1
    for (int zi = 0; zi < 8; ++zi) {
        f32x16 acc;
#pragma unroll
        for (int i = 0; i < 16; ++i) acc[i] = 0.f;

#pragma unroll
        for (int ks = 0; ks < 16; ++ks) {
            f16x8 u  = *(const f16x8*)(P1r + zi * 256 + ks * 16);   // uniform -> L1 bcast
            f16x8 pv = *(const f16x8*)(P2r + ks * 16);              // L1-resident
            f16x8 af = u * pv;                                       // 4x v_pk_mul_f16
            acc = __builtin_amdgcn_mfma_f32_32x32x16_f16(af, bq[ks], acc, 0, 0, 0);
        }

        // ---- acc -> LDS [dv][x][c] (stride 33; 2-way max = free) ----
        float* T = sT[zi & 1];
#pragma unroll
        for (int i = 0; i < 16; ++i) {
            const int xl = (i & 3) + 8 * (i >> 2) + 4 * kq;
            T[w * 1056 + xl * 33 + ln] = acc[i];
        }
        __syncthreads();

        // ---- transposed read + coalesced f32x4-over-dv stores ----
        const int z = z0 + zi;
#pragma unroll
        for (int j = 0; j < 4; ++j) {
            const int xl = xg * 4 + j;
            f32x4 v;
            v[0] = T[0 * 1056 + xl * 33 + cl];
            v[1] = T[1 * 1056 + xl * 33 + cl];
            v[2] = T[2 * 1056 + xl * 33 + cl];
            v[3] = T[3 * 1056 + xl * 33 + cl];
            const size_t idx = (size_t)((b * 128 + z) * 128 + x0 + xl) * 128 + c0 + cl;
            __builtin_nontemporal_store(v, (f32x4*)(out + idx * 4));
        }
        // no second barrier: next iter writes the other sT buffer
    }
}

extern "C" void kernel_launch(void* const* d_in, const int* in_sizes, int n_in,
                              void* d_out, int out_size, void* d_ws, size_t ws_size,
                              hipStream_t stream) {
    const float* x1 = (const float*)d_in[0];
    const float* x2 = (const float*)d_in[1];
    const float* x3 = (const float*)d_in[2];
    const float* W1 = (const float*)d_in[3];
    const float* b1 = (const float*)d_in[4];
    const float* W2 = (const float*)d_in[5];
    const float* b2 = (const float*)d_in[6];
    const float* W3 = (const float*)d_in[7];
    const float* b3 = (const float*)d_in[8];

    char* ws = (char*)d_ws;
    f16* p1 = (f16*)ws;                            // [16][128][256] f16 = 1 MB
    f16* p2 = (f16*)(ws + (1u << 20));             // 1 MB
    f16* p3 = (f16*)(ws + 2u * (1u << 20));        // 1 MB

    proj_kernel<<<dim3(32, 4, 3), 256, 0, stream>>>(x1, x2, x3, W1, b1, W2, b2, W3, b3,
                                                    p1, p2, p3);
    tri_kernel<<<dim3(1024), 256, 0, stream>>>(p1, p2, p3, (float*)d_out);
}

// Round 11
// 69.480 us; speedup vs baseline: 1.6807x; 1.1833x over previous
//
#include <hip/hip_runtime.h>
#include <hip/hip_bf16.h>

// FactorizedTrilinear: out[b,z,x,c,dv] = sum_e p1[b,z,dv,e] p2[b,x,dv,e] p3[b,c,dv,e]
// B=4, Z=128, DV=4, IN=512, R=256. Output 4*128^3*4 fp32 = 134 MB (write floor
// ~19 us @ 6.9 TB/s demonstrated by the harness fill).
// R11: R8's proven tri residency (pv[16]+bq[16] register-resident, sP1
// wave-private LDS, launch_bounds(256,2)) + two fixes aimed at the per-z-iter
// store drain: (1) double-buffered sT with an LGKM-ONLY barrier (hand-rolled
// s_waitcnt lgkmcnt(0) + s_barrier) so __syncthreads()'s implicit vmcnt(0)
// never drains the nontemporal output stores mid-loop; (2) the 16-MFMA serial
// accumulator chain split into two independent 8-chains (even/odd ks).
// proj unchanged from R8 (known-correct, ~12 us).

typedef _Float16 f16;
typedef __attribute__((ext_vector_type(8)))  _Float16 f16x8;
typedef __attribute__((ext_vector_type(4)))  float    f32x4;
typedef __attribute__((ext_vector_type(16))) float    f32x16;

// LDS-only barrier: waits local ds ops, does NOT drain global stores (vmcnt).
__device__ __forceinline__ void lds_barrier() {
    __builtin_amdgcn_sched_barrier(0);
    asm volatile("s_waitcnt lgkmcnt(0)" ::: "memory");
    __builtin_amdgcn_s_barrier();
    __builtin_amdgcn_sched_barrier(0);
}

// ---------------- Stage 1: projections via 32x32x16 f16 MFMA ----------------
// GEMM per matrix: M=2048 (m = b*512 + z*4 + dv), N=256, K=512.
// Block 256 thr = 4 waves (2m x 2n) -> tile 64m x 64n; grid (32,4,3).
__global__ __launch_bounds__(256) void proj_kernel(
    const float* __restrict__ x1, const float* __restrict__ x2, const float* __restrict__ x3,
    const float* __restrict__ W1, const float* __restrict__ b1,
    const float* __restrict__ W2, const float* __restrict__ b2,
    const float* __restrict__ W3, const float* __restrict__ b3,
    f16* __restrict__ p1, f16* __restrict__ p2, f16* __restrict__ p3) {
    const int mat = blockIdx.z;
    const float* __restrict__ x    = (mat == 0) ? x1 : (mat == 1) ? x2 : x3;
    const float* __restrict__ W    = (mat == 0) ? W1 : (mat == 1) ? W2 : W3;
    const float* __restrict__ bias = (mat == 0) ? b1 : (mat == 1) ? b2 : b3;
    f16* __restrict__ p = (mat == 0) ? p1 : (mat == 1) ? p2 : p3;

    const int tid  = threadIdx.x;
    const int lane = tid & 63;
    const int w    = tid >> 6;
    const int ln   = lane & 31;
    const int kq   = lane >> 5;
    const int m0   = blockIdx.x * 64 + (w >> 1) * 32;
    const int n0b  = blockIdx.y * 64;
    const int n0   = n0b + (w & 1) * 32;

    __shared__ f16 sWt[64 * 40];   // [n][k], row stride 40 f16

    f32x16 acc;
#pragma unroll
    for (int i = 0; i < 16; ++i) acc[i] = 0.f;

    const int snn = tid & 63, skk0 = tid >> 6;

#pragma unroll 1
    for (int ch = 0; ch < 16; ++ch) {
        const int k0 = ch * 32;
#pragma unroll
        for (int j = 0; j < 8; ++j) {
            const int kk = skk0 + 4 * j;
            sWt[snn * 40 + kk] = (f16)W[(size_t)(k0 + kk) * 256 + n0b + snn];
        }
        __syncthreads();
#pragma unroll
        for (int ks = 0; ks < 2; ++ks) {
            const float* X = x + (size_t)(m0 + ln) * 512 + k0 + ks * 16 + kq * 8;
            f32x4 a0 = *(const f32x4*)X;
            f32x4 a1 = *(const f32x4*)(X + 4);
            f16x8 av;
            av[0] = (f16)a0[0]; av[1] = (f16)a0[1]; av[2] = (f16)a0[2]; av[3] = (f16)a0[3];
            av[4] = (f16)a1[0]; av[5] = (f16)a1[1]; av[6] = (f16)a1[2]; av[7] = (f16)a1[3];
            f16x8 bv = *(const f16x8*)&sWt[((w & 1) * 32 + ln) * 40 + ks * 16 + kq * 8];
            acc = __builtin_amdgcn_mfma_f32_32x32x16_f16(av, bv, acc, 0, 0, 0);
        }
        __syncthreads();
    }

    // C/D map (m74/m101): col = lane&31 -> n, row = (i&3)+8*(i>>2)+4*kq -> m.
    const int n = n0 + ln;
    const float bn = bias[n];
#pragma unroll
    for (int i = 0; i < 16; ++i) {
        const int m  = m0 + (i & 3) + 8 * (i >> 2) + 4 * kq;
        const int bb = m >> 9, z = (m >> 2) & 127, dv = m & 3;
        p[((bb * 4 + dv) * 128 + z) * 256 + n] = (f16)(acc[i] + bn);
    }
}

// ---------------- Stage 2: trilinear ----------------
// Grid = b(4) x xt(4) x ct(4) x zg(16) = 1024 blocks; 256 thr = 4 waves,
// wave w = dv. Wave: 32x x 32c x 8z x 1dv.
// pv[16] (p2 x-rows) + bq[16] (p3 c-rows): full K=256 register-resident,
// z-invariant. p1 z-rows in wave-private sP1 (no barrier). Per z: two
// independent 8-MFMA chains (even/odd ks) -> acc sum -> sT[zi&1][dv][x][c]
// (stride 33) -> lgkm-only barrier -> transposed f32x4-over-dv nontemporal
// stores (never drained mid-loop).
__global__ __launch_bounds__(256, 2) void tri_kernel(
    const f16* __restrict__ p1, const f16* __restrict__ p2,
    const f16* __restrict__ p3, float* __restrict__ out) {
    const int bi = blockIdx.x;
    const int zg = bi & 15;
    const int ct = (bi >> 4) & 3;
    const int xt = (bi >> 6) & 3;
    const int b  = bi >> 8;

    const int tid  = threadIdx.x;
    const int lane = tid & 63;
    const int w    = tid >> 6;          // = dv
    const int ln   = lane & 31;
    const int kq   = lane >> 5;
    const int x0   = xt * 32;
    const int c0   = ct * 32;
    const int z0   = zg * 8;
    const int sl   = b * 4 + w;

    __shared__ __align__(16) f16 sP1[4][8 * 256];   // 16 KB, wave-private p1 rows
    __shared__ float sT[2][4 * 32 * 33];            // 2 x 16.5 KB transpose buffers

    // ---- stage this wave's p1 z-rows (wave-private: no barrier) ----
#pragma unroll
    for (int i = 0; i < 4; ++i) {
        const int G  = i * 64 + lane;
        const int zo = G >> 5, es = G & 31;
        f16x8 v = *(const f16x8*)(p1 + ((sl * 128 + z0 + zo) << 8) + es * 8);
        *(f16x8*)&sP1[w][G * 8] = v;
    }

    // ---- prologue: full-K fragments in registers (z-invariant) ----
    f16x8 pv[16], bq[16];
    const f16* P2r = p2 + ((sl * 128 + x0 + ln) << 8) + kq * 8;
    const f16* P3r = p3 + ((sl * 128 + c0 + ln) << 8) + kq * 8;
#pragma unroll
    for (int ks = 0; ks < 16; ++ks) {
        pv[ks] = *(const f16x8*)(P2r + ks * 16);
        bq[ks] = *(const f16x8*)(P3r + ks * 16);
    }

    const int cl = tid & 31, xg = tid >> 5;

#pragma unroll 1
    for (int zi = 0; zi < 8; ++zi) {
        f32x16 aL, aH;
#pragma unroll
        for (int i = 0; i < 16; ++i) { aL[i] = 0.f; aH[i] = 0.f; }

        // two independent 8-MFMA chains (even ks -> aL, odd ks -> aH)
#pragma unroll
        for (int kp = 0; kp < 8; ++kp) {
            const int ke = 2 * kp, ko = 2 * kp + 1;
            f16x8 ue = *(const f16x8*)&sP1[w][(zi * 32 + ke * 2 + kq) * 8];
            f16x8 uo = *(const f16x8*)&sP1[w][(zi * 32 + ko * 2 + kq) * 8];
            f16x8 ae = ue * pv[ke];
            f16x8 ao = uo * pv[ko];
            aL = __builtin_amdgcn_mfma_f32_32x32x16_f16(ae, bq[ke], aL, 0, 0, 0);
            aH = __builtin_amdgcn_mfma_f32_32x32x16_f16(ao, bq[ko], aH, 0, 0, 0);
        }

        // ---- acc -> LDS [dv][x][c] (stride 33; 2-way max = free) ----
        float* T = sT[zi & 1];
#pragma unroll
        for (int i = 0; i < 16; ++i) {
            const int xl = (i & 3) + 8 * (i >> 2) + 4 * kq;
            T[w * 1056 + xl * 33 + ln] = aL[i] + aH[i];
        }
        lds_barrier();   // lgkmcnt(0) + s_barrier: does NOT drain global stores

        // ---- transposed read + coalesced f32x4-over-dv nontemporal stores ----
        const int z = z0 + zi;
#pragma unroll
        for (int j = 0; j < 4; ++j) {
            const int xl = xg * 4 + j;
            f32x4 v;
            v[0] = T[0 * 1056 + xl * 33 + cl];
            v[1] = T[1 * 1056 + xl * 33 + cl];
            v[2] = T[2 * 1056 + xl * 33 + cl];
            v[3] = T[3 * 1056 + xl * 33 + cl];
            const size_t idx = (size_t)((b * 128 + z) * 128 + x0 + xl) * 128 + c0 + cl;
            __builtin_nontemporal_store(v, (f32x4*)(out + idx * 4));
        }
        // no second barrier: next iter writes the other sT buffer; a wave
        // passing the NEXT lds_barrier has finished this iter's reads.
    }
}

extern "C" void kernel_launch(void* const* d_in, const int* in_sizes, int n_in,
                              void* d_out, int out_size, void* d_ws, size_t ws_size,
                              hipStream_t stream) {
    const float* x1 = (const float*)d_in[0];
    const float* x2 = (const float*)d_in[1];
    const float* x3 = (const float*)d_in[2];
    const float* W1 = (const float*)d_in[3];
    const float* b1 = (const float*)d_in[4];
    const float* W2 = (const float*)d_in[5];
    const float* b2 = (const float*)d_in[6];
    const float* W3 = (const float*)d_in[7];
    const float* b3 = (const float*)d_in[8];

    char* ws = (char*)d_ws;
    f16* p1 = (f16*)ws;                            // [16][128][256] f16 = 1 MB
    f16* p2 = (f16*)(ws + (1u << 20));             // 1 MB
    f16* p3 = (f16*)(ws + 2u * (1u << 20));        // 1 MB

    proj_kernel<<<dim3(32, 4, 3), 256, 0, stream>>>(x1, x2, x3, W1, b1, W2, b2, W3, b3,
                                                    p1, p2, p3);
    tri_kernel<<<dim3(1024), 256, 0, stream>>>(p1, p2, p3, (float*)d_out);
}

// Round 12
// 69.448 us; speedup vs baseline: 1.6814x; 1.0005x over previous
//
#include <hip/hip_runtime.h>
#include <hip/hip_bf16.h>

// FactorizedTrilinear: out[b,z,x,c,dv] = sum_e p1[b,z,dv,e] p2[b,x,dv,e] p3[b,c,dv,e]
// B=4, Z=128, DV=4, IN=512, R=256. Output 4*128^3*4 fp32 = 134 MB (write floor
// ~19 us @ 6.9 TB/s demonstrated by the harness fill).
// R12: occupancy attack. Every tri since R6 held 128+ regs of fragments/wave ->
// 2 waves/SIMD -> nothing hides L2/HBM latency. Now block = 512 thr = 8 waves
// = (dv 0..3) x (K-half h 0..1); per wave pv[8]+bq[8] = 64 regs + acc 16 ->
// ~110 unified -> 4 waves/SIMD (2 blocks/CU, LDS 66 KB). K-halves summed in
// the LDS-transpose epilogue (2 reads + add per dv). p1 row streamed from
// global (wave-uniform -> broadcast; R6-proven exact FETCH). One lgkm-only
// barrier per z-iter (double-buffered sS). proj: 128-k super-chunk staging
// (8 barriers instead of 32, 32-deep load bursts).

typedef _Float16 f16;
typedef __attribute__((ext_vector_type(8)))  _Float16 f16x8;
typedef __attribute__((ext_vector_type(4)))  float    f32x4;
typedef __attribute__((ext_vector_type(16))) float    f32x16;

// LDS-only barrier: waits local ds ops, does NOT drain global stores (vmcnt).
__device__ __forceinline__ void lds_barrier() {
    __builtin_amdgcn_sched_barrier(0);
    asm volatile("s_waitcnt lgkmcnt(0)" ::: "memory");
    __builtin_amdgcn_s_barrier();
    __builtin_amdgcn_sched_barrier(0);
}

// ---------------- Stage 1: projections via 32x32x16 f16 MFMA ----------------
// GEMM per matrix: M=2048 (m = b*512 + z*4 + dv), N=256, K=512.
// Block 256 thr = 4 waves (2m x 2n) -> tile 64m x 64n; grid (32,4,3).
// 4 super-chunks of 128k: stage W[128k][64n] -> sWt[n][k] f16 (stride 132),
// then 8 MFMA steps; 8 barriers total (was 32).
__global__ __launch_bounds__(256) void proj_kernel(
    const float* __restrict__ x1, const float* __restrict__ x2, const float* __restrict__ x3,
    const float* __restrict__ W1, const float* __restrict__ b1,
    const float* __restrict__ W2, const float* __restrict__ b2,
    const float* __restrict__ W3, const float* __restrict__ b3,
    f16* __restrict__ p1, f16* __restrict__ p2, f16* __restrict__ p3) {
    const int mat = blockIdx.z;
    const float* __restrict__ x    = (mat == 0) ? x1 : (mat == 1) ? x2 : x3;
    const float* __restrict__ W    = (mat == 0) ? W1 : (mat == 1) ? W2 : W3;
    const float* __restrict__ bias = (mat == 0) ? b1 : (mat == 1) ? b2 : b3;
    f16* __restrict__ p = (mat == 0) ? p1 : (mat == 1) ? p2 : p3;

    const int tid  = threadIdx.x;
    const int lane = tid & 63;
    const int w    = tid >> 6;
    const int ln   = lane & 31;
    const int kq   = lane >> 5;
    const int m0   = blockIdx.x * 64 + (w >> 1) * 32;
    const int n0b  = blockIdx.y * 64;
    const int n0   = n0b + (w & 1) * 32;

    __shared__ f16 sWt[64 * 132];   // [n][k], row stride 132 f16 (16.9 KB)

    f32x16 acc;
#pragma unroll
    for (int i = 0; i < 16; ++i) acc[i] = 0.f;

    const int snn = tid & 63, skk0 = tid >> 6;

#pragma unroll 1
    for (int sc = 0; sc < 4; ++sc) {
        const int k0 = sc * 128;
        // stage W super-chunk: [128k][64n] -> sWt[n][k] f16
#pragma unroll
        for (int j = 0; j < 32; ++j) {
            const int kk = skk0 + 4 * j;
            sWt[snn * 132 + kk] = (f16)W[(size_t)(k0 + kk) * 256 + n0b + snn];
        }
        __syncthreads();
#pragma unroll
        for (int ks = 0; ks < 8; ++ks) {
            const float* X = x + (size_t)(m0 + ln) * 512 + k0 + ks * 16 + kq * 8;
            f32x4 a0 = *(const f32x4*)X;
            f32x4 a1 = *(const f32x4*)(X + 4);
            f16x8 av;
            av[0] = (f16)a0[0]; av[1] = (f16)a0[1]; av[2] = (f16)a0[2]; av[3] = (f16)a0[3];
            av[4] = (f16)a1[0]; av[5] = (f16)a1[1]; av[6] = (f16)a1[2]; av[7] = (f16)a1[3];
            f16x8 bv = *(const f16x8*)&sWt[((w & 1) * 32 + ln) * 132 + ks * 16 + kq * 8];
            acc = __builtin_amdgcn_mfma_f32_32x32x16_f16(av, bv, acc, 0, 0, 0);
        }
        __syncthreads();
    }

    // C/D map (m74/m101): col = lane&31 -> n, row = (i&3)+8*(i>>2)+4*kq -> m.
    const int n = n0 + ln;
    const float bn = bias[n];
#pragma unroll
    for (int i = 0; i < 16; ++i) {
        const int m  = m0 + (i & 3) + 8 * (i >> 2) + 4 * kq;
        const int bb = m >> 9, z = (m >> 2) & 127, dv = m & 3;
        p[((bb * 4 + dv) * 128 + z) * 256 + n] = (f16)(acc[i] + bn);
    }
}

// ---------------- Stage 2: trilinear, K-split for occupancy ----------------
// Grid = b(4) x xt(4) x ct(4) x zg(16) = 1024 blocks; 512 thr = 8 waves,
// wave w: dv = w&3, K-half h = w>>2 (e in [h*128, h*128+128)).
// Per wave: pv[8] (p2 x-rows) + bq[8] (p3 c-rows) register-resident (64 VGPR),
// acc 16 -> ~110 unified regs -> 4 waves/SIMD, 2 blocks/CU (LDS 66 KB).
// Per z: 8-MFMA chain (u = p1 row from global, uniform broadcast) ->
// sS[buf][h][dv][x][33] -> lgkm barrier -> epilogue sums h=0+h=1, f32x4-over-dv
// coalesced nontemporal stores.
__global__ __launch_bounds__(512, 4) void tri_kernel(
    const f16* __restrict__ p1, const f16* __restrict__ p2,
    const f16* __restrict__ p3, float* __restrict__ out) {
    const int bi = blockIdx.x;
    const int zg = bi & 15;
    const int ct = (bi >> 4) & 3;
    const int xt = (bi >> 6) & 3;
    const int b  = bi >> 8;

    const int tid  = threadIdx.x;
    const int lane = tid & 63;
    const int w    = tid >> 6;
    const int dv   = w & 3;
    const int h    = w >> 2;            // K-half
    const int ln   = lane & 31;
    const int kq   = lane >> 5;
    const int x0   = xt * 32;
    const int c0   = ct * 32;
    const int z0   = zg * 8;
    const int sl   = b * 4 + dv;

    __shared__ float sS[2 * 2 * 4 * 32 * 33];   // [buf][h][dv][x][33] = 66 KB

    // ---- prologue: this wave's K-half fragments, register-resident ----
    f16x8 pv[8], bq[8];
    const f16* P2r = p2 + ((sl * 128 + x0 + ln) << 8) + h * 128 + kq * 8;
    const f16* P3r = p3 + ((sl * 128 + c0 + ln) << 8) + h * 128 + kq * 8;
#pragma unroll
    for (int k = 0; k < 8; ++k) {
        pv[k] = *(const f16x8*)(P2r + k * 16);
        bq[k] = *(const f16x8*)(P3r + k * 16);
    }
    const f16* P1r = p1 + ((sl * 128 + z0) << 8) + h * 128 + kq * 8;  // +256 per z

    const int cl = tid & 31, xg = tid >> 5;   // epilogue mapping (16 xg x 32 cl)

#pragma unroll 1
    for (int zi = 0; zi < 8; ++zi) {
        f32x16 acc;
#pragma unroll
        for (int i = 0; i < 16; ++i) acc[i] = 0.f;

#pragma unroll
        for (int k = 0; k < 8; ++k) {
            f16x8 u  = *(const f16x8*)(P1r + zi * 256 + k * 16);  // uniform -> bcast
            f16x8 af = u * pv[k];                                  // 4x v_pk_mul_f16
            acc = __builtin_amdgcn_mfma_f32_32x32x16_f16(af, bq[k], acc, 0, 0, 0);
        }

        // ---- acc -> sS[buf][h][dv][x][33] (banks (x+c)%32: 2-way = free) ----
        float* T = &sS[(((zi & 1) * 2 + h) * 4 + dv) * 1056];
#pragma unroll
        for (int i = 0; i < 16; ++i) {
            const int xl = (i & 3) + 8 * (i >> 2) + 4 * kq;
            T[xl * 33 + ln] = acc[i];
        }
        lds_barrier();   // lgkmcnt(0) + s_barrier: does NOT drain global stores

        // ---- epilogue: sum K-halves, f32x4-over-dv coalesced NT stores ----
        const float* S0 = &sS[((zi & 1) * 2 + 0) * 4 * 1056];
        const float* S1 = &sS[((zi & 1) * 2 + 1) * 4 * 1056];
        const int z = z0 + zi;
#pragma unroll
        for (int j = 0; j < 2; ++j) {
            const int xl = xg * 2 + j;
            f32x4 v;
#pragma unroll
            for (int d = 0; d < 4; ++d)
                v[d] = S0[d * 1056 + xl * 33 + cl] + S1[d * 1056 + xl * 33 + cl];
            const size_t idx = (size_t)((b * 128 + z) * 128 + x0 + xl) * 128 + c0 + cl;
            __builtin_nontemporal_store(v, (f32x4*)(out + idx * 4));
        }
        // no second barrier: next iter writes the other sS buffer.
    }
}

extern "C" void kernel_launch(void* const* d_in, const int* in_sizes, int n_in,
                              void* d_out, int out_size, void* d_ws, size_t ws_size,
                              hipStream_t stream) {
    const float* x1 = (const float*)d_in[0];
    const float* x2 = (const float*)d_in[1];
    const float* x3 = (const float*)d_in[2];
    const float* W1 = (const float*)d_in[3];
    const float* b1 = (const float*)d_in[4];
    const float* W2 = (const float*)d_in[5];
    const float* b2 = (const float*)d_in[6];
    const float* W3 = (const float*)d_in[7];
    const float* b3 = (const float*)d_in[8];

    char* ws = (char*)d_ws;
    f16* p1 = (f16*)ws;                            // [16][128][256] f16 = 1 MB
    f16* p2 = (f16*)(ws + (1u << 20));             // 1 MB
    f16* p3 = (f16*)(ws + 2u * (1u << 20));        // 1 MB

    proj_kernel<<<dim3(32, 4, 3), 256, 0, stream>>>(x1, x2, x3, W1, b1, W2, b2, W3, b3,
                                                    p1, p2, p3);
    tri_kernel<<<dim3(1024), 512, 0, stream>>>(p1, p2, p3, (float*)d_out);
}

// Round 13
// 62.594 us; speedup vs baseline: 1.8656x; 1.1095x over previous
//
#include <hip/hip_runtime.h>
#include <hip/hip_bf16.h>

// FactorizedTrilinear: out[b,z,x,c,dv] = sum_e p1[b,z,dv,e] p2[b,x,dv,e] p3[b,c,dv,e]
// B=4, Z=128, DV=4, IN=512, R=256. Output 4*128^3*4 fp32 = 134 MB (write floor
// ~19 us @ 6.9 TB/s demonstrated by the harness fill).
// R13: R8 EXACTLY (best measured total, 64.9 us), ONE change: plain stores
// instead of __builtin_nontemporal_store. Theory: NT bypasses L2 write-back /
// write-combining and pins the store path at ~2.7 TB/s (observed in every NT
// variant regardless of occupancy/barriers/residency — all those levers were
// individually disproven in R9-R12). Plain stores drain via L2 like the
// harness fill that sustains 6.9 TB/s.

typedef _Float16 f16;
typedef __attribute__((ext_vector_type(8)))  _Float16 f16x8;
typedef __attribute__((ext_vector_type(4)))  float    f32x4;
typedef __attribute__((ext_vector_type(16))) float    f32x16;

// ---------------- Stage 1: projections via 32x32x16 f16 MFMA ----------------
// GEMM per matrix: M=2048 (m = b*512 + z*4 + dv), N=256, K=512.
// Block 256 thr = 4 waves (2m x 2n) -> tile 64m x 64n; grid (32,4,3).
// Per 32-k chunk: stage W[32k][64n] -> LDS as sWt[n][k] f16 (row stride 40),
// A-frag per-lane direct from x (f32->f16).
__global__ __launch_bounds__(256) void proj_kernel(
    const float* __restrict__ x1, const float* __restrict__ x2, const float* __restrict__ x3,
    const float* __restrict__ W1, const float* __restrict__ b1,
    const float* __restrict__ W2, const float* __restrict__ b2,
    const float* __restrict__ W3, const float* __restrict__ b3,
    f16* __restrict__ p1, f16* __restrict__ p2, f16* __restrict__ p3) {
    const int mat = blockIdx.z;
    const float* __restrict__ x    = (mat == 0) ? x1 : (mat == 1) ? x2 : x3;
    const float* __restrict__ W    = (mat == 0) ? W1 : (mat == 1) ? W2 : W3;
    const float* __restrict__ bias = (mat == 0) ? b1 : (mat == 1) ? b2 : b3;
    f16* __restrict__ p = (mat == 0) ? p1 : (mat == 1) ? p2 : p3;

    const int tid  = threadIdx.x;
    const int lane = tid & 63;
    const int w    = tid >> 6;
    const int ln   = lane & 31;
    const int kq   = lane >> 5;
    const int m0   = blockIdx.x * 64 + (w >> 1) * 32;
    const int n0b  = blockIdx.y * 64;
    const int n0   = n0b + (w & 1) * 32;

    __shared__ f16 sWt[64 * 40];   // [n][k], row stride 40 f16

    f32x16 acc;
#pragma unroll
    for (int i = 0; i < 16; ++i) acc[i] = 0.f;

    const int snn = tid & 63, skk0 = tid >> 6;

#pragma unroll 1
    for (int ch = 0; ch < 16; ++ch) {
        const int k0 = ch * 32;
        // stage W chunk: [32k][64n] -> sWt[n][k] f16
#pragma unroll
        for (int j = 0; j < 8; ++j) {
            const int kk = skk0 + 4 * j;
            sWt[snn * 40 + kk] = (f16)W[(size_t)(k0 + kk) * 256 + n0b + snn];
        }
        __syncthreads();
#pragma unroll
        for (int ks = 0; ks < 2; ++ks) {
            const float* X = x + (size_t)(m0 + ln) * 512 + k0 + ks * 16 + kq * 8;
            f32x4 a0 = *(const f32x4*)X;
            f32x4 a1 = *(const f32x4*)(X + 4);
            f16x8 av;
            av[0] = (f16)a0[0]; av[1] = (f16)a0[1]; av[2] = (f16)a0[2]; av[3] = (f16)a0[3];
            av[4] = (f16)a1[0]; av[5] = (f16)a1[1]; av[6] = (f16)a1[2]; av[7] = (f16)a1[3];
            f16x8 bv = *(const f16x8*)&sWt[((w & 1) * 32 + ln) * 40 + ks * 16 + kq * 8];
            acc = __builtin_amdgcn_mfma_f32_32x32x16_f16(av, bv, acc, 0, 0, 0);
        }
        __syncthreads();
    }

    // C/D map (m74/m101): col = lane&31 -> n, row = (i&3)+8*(i>>2)+4*kq -> m.
    const int n = n0 + ln;
    const float bn = bias[n];
#pragma unroll
    for (int i = 0; i < 16; ++i) {
        const int m  = m0 + (i & 3) + 8 * (i >> 2) + 4 * kq;
        const int bb = m >> 9, z = (m >> 2) & 127, dv = m & 3;
        p[((bb * 4 + dv) * 128 + z) * 256 + n] = (f16)(acc[i] + bn);
    }
}

// ---------------- Stage 2: trilinear, reg-resident frags + LDS transpose ----------------
// Grid = b(4) x xt(4) x ct(4) x zg(16), zg fastest = 1024 blocks; 256 thr,
// 4 waves, wave w = dv. Wave: 32x x 32c x 8z x 1dv.
// pv[16] (p2 x-rows), bq[16] (p3 c-rows): full K=256 in 128 VGPRs, z-invariant.
// Per z: 16 uniform LDS reads (p1) + 64 pk_mul + 16 MFMA; acc -> sT[dv][x][c]
// (stride 33, conflict-free), barrier, all threads read f32x4-over-dv ->
// coalesced 16B PLAIN stores (L2 write-back), barrier.
__global__ __launch_bounds__(256, 2) void tri_kernel(
    const f16* __restrict__ p1, const f16* __restrict__ p2,
    const f16* __restrict__ p3, float* __restrict__ out) {
    const int bi = blockIdx.x;
    const int zg = bi & 15;
    const int ct = (bi >> 4) & 3;
    const int xt = (bi >> 6) & 3;
    const int b  = bi >> 8;

    const int tid  = threadIdx.x;
    const int lane = tid & 63;
    const int w    = tid >> 6;          // = dv
    const int ln   = lane & 31;
    const int kq   = lane >> 5;
    const int x0   = xt * 32;
    const int c0   = ct * 32;
    const int z0   = zg * 8;
    const int sl   = b * 4 + w;

    __shared__ __align__(16) f16  sP1[4][8 * 256];   // 16 KB, wave-private p1 rows
    __shared__ float sT[4 * 32 * 33];                 // 16.5 KB transpose buffer

    // ---- stage this wave's p1 z-rows (no barrier needed: wave-private) ----
#pragma unroll
    for (int i = 0; i < 4; ++i) {
        const int G  = i * 64 + lane;
        const int zo = G >> 5, es = G & 31;
        f16x8 v = *(const f16x8*)(p1 + ((sl * 128 + z0 + zo) << 8) + es * 8);
        *(f16x8*)&sP1[w][G * 8] = v;
    }

    // ---- prologue: full-K fragments in registers (z-invariant) ----
    f16x8 pv[16], bq[16];
    const f16* P2r = p2 + ((sl * 128 + x0 + ln) << 8) + kq * 8;
    const f16* P3r = p3 + ((sl * 128 + c0 + ln) << 8) + kq * 8;
#pragma unroll
    for (int ks = 0; ks < 16; ++ks) {
        pv[ks] = *(const f16x8*)(P2r + ks * 16);
        bq[ks] = *(const f16x8*)(P3r + ks * 16);
    }

    const int cl = tid & 31, xg = tid >> 5;

#pragma unroll 1
    for (int zi = 0; zi < 8; ++zi) {
        f32x16 acc;
#pragma unroll
        for (int i = 0; i < 16; ++i) acc[i] = 0.f;

#pragma unroll
        for (int ks = 0; ks < 16; ++ks) {
            f16x8 u = *(const f16x8*)&sP1[w][(zi * 32 + ks * 2 + kq) * 8];  // broadcast
            f16x8 af = u * pv[ks];        // 4x v_pk_mul_f16
            acc = __builtin_amdgcn_mfma_f32_32x32x16_f16(af, bq[ks], acc, 0, 0, 0);
        }

        // ---- acc -> LDS [dv][x][c] (stride 33: conflict-free) ----
#pragma unroll
        for (int i = 0; i < 16; ++i) {
            const int xl = (i & 3) + 8 * (i >> 2) + 4 * kq;
            sT[w * 1056 + xl * 33 + ln] = acc[i];
        }
        __syncthreads();

        // ---- transposed read + coalesced f32x4-over-dv PLAIN stores ----
        const int z = z0 + zi;
#pragma unroll
        for (int j = 0; j < 4; ++j) {
            const int xl = xg * 4 + j;
            f32x4 v;
            v[0] = sT[0 * 1056 + xl * 33 + cl];
            v[1] = sT[1 * 1056 + xl * 33 + cl];
            v[2] = sT[2 * 1056 + xl * 33 + cl];
            v[3] = sT[3 * 1056 + xl * 33 + cl];
            const size_t idx = (size_t)((b * 128 + z) * 128 + x0 + xl) * 128 + c0 + cl;
            *(f32x4*)(out + idx * 4) = v;   // plain store: L2 write-back path
        }
        __syncthreads();
    }
}

extern "C" void kernel_launch(void* const* d_in, const int* in_sizes, int n_in,
                              void* d_out, int out_size, void* d_ws, size_t ws_size,
                              hipStream_t stream) {
    const float* x1 = (const float*)d_in[0];
    const float* x2 = (const float*)d_in[1];
    const float* x3 = (const float*)d_in[2];
    const float* W1 = (const float*)d_in[3];
    const float* b1 = (const float*)d_in[4];
    const float* W2 = (const float*)d_in[5];
    const float* b2 = (const float*)d_in[6];
    const float* W3 = (const float*)d_in[7];
    const float* b3 = (const float*)d_in[8];

    char* ws = (char*)d_ws;
    f16* p1 = (f16*)ws;                            // [16][128][256] f16 = 1 MB
    f16* p2 = (f16*)(ws + (1u << 20));             // 1 MB
    f16* p3 = (f16*)(ws + 2u * (1u << 20));        // 1 MB

    proj_kernel<<<dim3(32, 4, 3), 256, 0, stream>>>(x1, x2, x3, W1, b1, W2, b2, W3, b3,
                                                    p1, p2, p3);
    tri_kernel<<<dim3(1024), 256, 0, stream>>>(p1, p2, p3, (float*)d_out);
}